// Round 11
// baseline (159.495 us; speedup 1.0000x reference)
//
#include <hip/hip_runtime.h>

#define B_  4
#define QL  128
#define CL  512
#define XD  64
#define ED  128
#define DD  128
#define YD  32

typedef __attribute__((ext_vector_type(8))) _Float16 f16x8;
typedef __attribute__((ext_vector_type(4))) float f32x4;

__device__ __forceinline__ float rdlane(float v, int l) {
  return __uint_as_float(__builtin_amdgcn_readlane(__float_as_uint(v), l));
}

// Fully self-contained: one block = (batch b, 2 q-rows). fp recomputed per block
// via MFMA (16.8 MFLOP/block). No workspace, no flags, no cross-block traffic.
// h1t is WAVE-PRIVATE (wave w owns rows w*16..+16 of each c-tile): written by the
// fp-GEMM, read by the main GEMM of the same wave -> no barriers in the t-loop.
// LDS swizzle: byte(c,d) = c*256 + ((((2d)>>4) ^ (c&7))<<4) + ((2d)&15).
__launch_bounds__(512, 2)
__global__ void fused_kernel(const float* __restrict__ qg,
                             const float* __restrict__ fg,
                             const float* __restrict__ lgg,
                             const float* __restrict__ W0,
                             const float* __restrict__ b0,
                             const float* __restrict__ W1,
                             const float* __restrict__ b1,
                             const float* __restrict__ Wo,
                             const float* __restrict__ bo,
                             float* __restrict__ out) {
  __shared__ __align__(16) _Float16 wf0[2048 * 8];   // 32 KB  W0f B-frags [(kk*8+jt)*64+lane][8]
  __shared__ __align__(16) _Float16 wf1[2048 * 8];   // 32 KB  W1  B-frags, same order
  __shared__ __align__(16) _Float16 h1t[8][16 * 128];// 32 KB  per-wave fp tile, swizzled
  __shared__ __align__(16) float att[2][CL];         //  4 KB
  __shared__ __align__(16) _Float16 qp16[2][DD];     // 512 B
  __shared__ float g[2][8][DD];                      //  8 KB
  __shared__ float red[16];
  __shared__ float part[2][8][YD];                   //  2 KB

  const int tid = threadIdx.x;
  const int bid = blockIdx.x;            // b*64 + qpair
  const int wid = tid >> 6, ln = tid & 63;
  const int b = bid >> 6, qpair = bid & 63;
  const int lhi = ln >> 4, llo = ln & 15;

  // ===== prologue: stage W0f + W1 fragments into LDS (coalesced-ish, L2-hot) =====
  #pragma unroll
  for (int i = 0; i < 4; ++i) {
    int F = i * 512 + tid;               // 0..2047: frag id (kk*8+jt)*64 + lane
    int lane = F & 63, jt = (F >> 6) & 7, kk = F >> 9;
    int col = jt * 16 + (lane & 15);
    int krow = kk * 32 + (lane >> 4) * 8;
    f16x8 v0, v1;
    #pragma unroll
    for (int e = 0; e < 8; ++e) {
      v0[e] = (_Float16)W0[(XD + krow + e) * DD + col];
      v1[e] = (_Float16)W1[(krow + e) * DD + col];
    }
    *(f16x8*)(wf0 + (size_t)F * 8) = v0;
    *(f16x8*)(wf1 + (size_t)F * 8) = v1;
  }

  // ===== softmax for the 2 q rows =====
  {
    const int q_ = tid >> 8, i = tid & 255;
    const float* lgr = lgg + ((size_t)(b * QL + qpair * 2 + q_)) * CL;
    float l0 = lgr[i], l1 = lgr[i + 256];
    float m = fmaxf(l0, l1);
    #pragma unroll
    for (int off = 1; off < 64; off <<= 1) m = fmaxf(m, __shfl_xor(m, off, 64));
    if (ln == 0) red[wid] = m;
    __syncthreads();
    m = fmaxf(fmaxf(red[q_ * 4], red[q_ * 4 + 1]), fmaxf(red[q_ * 4 + 2], red[q_ * 4 + 3]));
    float p0 = expf(l0 - m), p1 = expf(l1 - m);
    float s = p0 + p1;
    #pragma unroll
    for (int off = 1; off < 64; off <<= 1) s += __shfl_xor(s, off, 64);
    if (ln == 0) red[8 + wid] = s;
    __syncthreads();
    float inv = 1.f / (red[8 + q_ * 4] + red[9 + q_ * 4] + red[10 + q_ * 4] + red[11 + q_ * 4]);
    att[q_][i] = p0 * inv;
    att[q_][i + 256] = p1 * inv;
  }

  // ===== qp for the 2 q rows =====
  if (tid < 256) {
    const int q_ = tid >> 7, d = tid & 127;
    const float* qr = qg + ((size_t)(b * QL + qpair * 2 + q_)) * XD;
    float qv = qr[ln];
    float acc = b0[d];
    const float* w = W0 + d;
    #pragma unroll
    for (int x = 0; x < XD; ++x)
      acc = fmaf(rdlane(qv, x), w[x * DD], acc);
    qp16[q_][d] = (_Float16)acc;
  }
  __syncthreads();                       // wf0/wf1/att/qp16 visible; LAST barrier

  f16x8 qpv[2][4];
  #pragma unroll
  for (int q_ = 0; q_ < 2; ++q_)
    #pragma unroll
    for (int kk = 0; kk < 4; ++kk)
      qpv[q_][kk] = *(const f16x8*)(&qp16[q_][kk * 32 + lhi * 8]);

  float b1v[8];
  #pragma unroll
  for (int jt = 0; jt < 8; ++jt) b1v[jt] = b1[jt * 16 + llo];

  float gp[2][8];
  #pragma unroll
  for (int q_ = 0; q_ < 2; ++q_)
    #pragma unroll
    for (int jt = 0; jt < 8; ++jt) gp[q_][jt] = 0.f;

  const f16x8 zf = {};
  char* const h1base = (char*)&h1t[wid][0];

  // ===== main loop: 4 c-tiles, barrier-free =====
  for (int t = 0; t < 4; ++t) {
    // --- fp-GEMM: this wave's 16 c-rows x 128 d, A = f (f16-cast), B = wf0 ---
    const float* fbase = fg + ((size_t)(b * CL + t * 128 + wid * 16 + llo)) * ED;
    f16x8 fa[4];
    #pragma unroll
    for (int kk = 0; kk < 4; ++kk) {
      f32x4 lo = *(const f32x4*)(fbase + kk * 32 + lhi * 8);
      f32x4 hi = *(const f32x4*)(fbase + kk * 32 + lhi * 8 + 4);
      f16x8 v;
      #pragma unroll
      for (int j = 0; j < 4; ++j) { v[j] = (_Float16)lo[j]; v[4 + j] = (_Float16)hi[j]; }
      fa[kk] = v;
    }
    f32x4 facc[8];
    #pragma unroll
    for (int jt = 0; jt < 8; ++jt) facc[jt] = (f32x4){0.f, 0.f, 0.f, 0.f};
    #pragma unroll
    for (int kk = 0; kk < 4; ++kk) {
      #pragma unroll
      for (int jt = 0; jt < 8; ++jt) {
        f16x8 wv = *(const f16x8*)(wf0 + (size_t)((kk * 8 + jt) * 64 + ln) * 8);
        facc[jt] = __builtin_amdgcn_mfma_f32_16x16x32_f16(fa[kk], wv, facc[jt], 0, 0, 0);
      }
    }
    // write fp tile to wave-private swizzled LDS (D-layout: row c=(ln>>4)*4+r, col d=jt*16+llo)
    #pragma unroll
    for (int jt = 0; jt < 8; ++jt) {
      const int dby = (jt * 16 + llo) * 2;
      #pragma unroll
      for (int r = 0; r < 4; ++r) {
        const int c = (ln >> 4) * 4 + r;
        const int off = c * 256 + ((((dby >> 4) ^ (c & 7)) << 4) | (dby & 15));
        *(_Float16*)(h1base + off) = (_Float16)facc[jt][r];
      }
    }
    // --- main GEMM: A = relu(fp + qp), B = wf1 (compiler inserts lgkmcnt) ---
    f32x4 acc[2][8];
    #pragma unroll
    for (int q_ = 0; q_ < 2; ++q_)
      #pragma unroll
      for (int jt = 0; jt < 8; ++jt)
        acc[q_][jt] = (f32x4){b1v[jt], b1v[jt], b1v[jt], b1v[jt]};   // b1 folded

    #pragma unroll
    for (int kk = 0; kk < 4; ++kk) {
      const int gr = (4 * kk + lhi) ^ (llo & 7);
      f16x8 araw = *(const f16x8*)(h1base + llo * 256 + gr * 16);
      f16x8 a0 = __builtin_elementwise_max(araw + qpv[0][kk], zf);
      f16x8 a1 = __builtin_elementwise_max(araw + qpv[1][kk], zf);
      #pragma unroll
      for (int jt = 0; jt < 8; ++jt) {
        f16x8 wv = *(const f16x8*)(wf1 + (size_t)((kk * 8 + jt) * 64 + ln) * 8);
        acc[0][jt] = __builtin_amdgcn_mfma_f32_16x16x32_f16(a0, wv, acc[0][jt], 0, 0, 0);
        acc[1][jt] = __builtin_amdgcn_mfma_f32_16x16x32_f16(a1, wv, acc[1][jt], 0, 0, 0);
      }
    }

    // epilogue: gp[q][jt] += att[q][c] * relu(H2)  (Wo GEMM commuted away)
    const int cb = t * 128 + wid * 16 + lhi * 4;
    #pragma unroll
    for (int q_ = 0; q_ < 2; ++q_) {
      f32x4 a4 = *(const f32x4*)&att[q_][cb];
      #pragma unroll
      for (int r = 0; r < 4; ++r)
        #pragma unroll
        for (int jt = 0; jt < 8; ++jt)
          gp[q_][jt] = fmaf(a4[r], fmaxf(acc[q_][jt][r], 0.f), gp[q_][jt]);
    }
  }

  // ===== reduce + y = g @ Wo + bo =====
  #pragma unroll
  for (int q_ = 0; q_ < 2; ++q_)
    #pragma unroll
    for (int jt = 0; jt < 8; ++jt) {
      gp[q_][jt] += __shfl_xor(gp[q_][jt], 16, 64);
      gp[q_][jt] += __shfl_xor(gp[q_][jt], 32, 64);
    }
  if (ln < 16) {
    #pragma unroll
    for (int q_ = 0; q_ < 2; ++q_)
      #pragma unroll
      for (int jt = 0; jt < 8; ++jt) g[q_][wid][jt * 16 + ln] = gp[q_][jt];
  }
  __syncthreads();

  {
    const int q_ = tid >> 8, rem = tid & 255;
    const int ch = rem >> 5, y = rem & 31;
    float a = 0.f;
    #pragma unroll
    for (int jj = 0; jj < 16; ++jj) {
      int j = ch * 16 + jj;
      float gj = g[q_][0][j] + g[q_][1][j] + g[q_][2][j] + g[q_][3][j]
               + g[q_][4][j] + g[q_][5][j] + g[q_][6][j] + g[q_][7][j];
      a = fmaf(gj, Wo[j * YD + y], a);
    }
    part[q_][ch][y] = a;
  }
  __syncthreads();
  if (tid < 64) {
    const int q_ = tid >> 5, y = tid & 31;
    float a = bo[y];
    #pragma unroll
    for (int ch = 0; ch < 8; ++ch) a += part[q_][ch][y];
    out[((size_t)(b * QL + qpair * 2 + q_)) * YD + y] = a;
  }
}

extern "C" void kernel_launch(void* const* d_in, const int* in_sizes, int n_in,
                              void* d_out, int out_size, void* d_ws, size_t ws_size,
                              hipStream_t stream) {
  const float* q  = (const float*)d_in[0];
  const float* f  = (const float*)d_in[1];
  const float* lg = (const float*)d_in[2];
  const float* W0 = (const float*)d_in[3];
  const float* b0 = (const float*)d_in[4];
  const float* W1 = (const float*)d_in[5];
  const float* b1 = (const float*)d_in[6];
  const float* Wo = (const float*)d_in[7];
  const float* bo = (const float*)d_in[8];
  float* out = (float*)d_out;

  fused_kernel<<<256, 512, 0, stream>>>(q, f, lg, W0, b0, W1, b1, Wo, bo, out);
}

// Round 12
// 28.499 us; speedup vs baseline: 5.5966x; 5.5966x over previous
//
#include <hip/hip_runtime.h>

#define B_  4
#define QL  128
#define CL  512
#define XD  64
#define ED  128
#define DD  128
#define YD  32

typedef __attribute__((ext_vector_type(8))) _Float16 f16x8;
typedef __attribute__((ext_vector_type(4))) float f32x4;

// ws layout (16B-aligned):
//   fph : f16 [512 chunks][64 lanes][8 e] = 512 KB  fragment-ordered f-part
//         chunk = ((b*4+t)*4+kk)*8 + wrow*4 + ct ; holds
//         fp[b][t*128+wrow*64+ct*16+llo][kk*32+lhi*8+e] at lane lhi*16+llo, elem e
//   qph : f16 [B_*QL*DD] = 128 KB  q-part + b0, linear [row][d]
//   w1f : f16 [16384]    =  32 KB  W1 B-frags [wcol][kk][jt][lane][8e]
__global__ void prep_kernel(const float* __restrict__ qg,
                            const float* __restrict__ fg,
                            const float* __restrict__ W0,
                            const float* __restrict__ b0,
                            const float* __restrict__ W1,
                            _Float16* __restrict__ fph,
                            _Float16* __restrict__ qph,
                            _Float16* __restrict__ w1f) {
  const int bid = blockIdx.x, tid = threadIdx.x;
  __shared__ __align__(16) float fr[128][20];
  __shared__ float w1s[32][65];

  if (bid < 128) {
    // ---- fp: 16 global rows per block, fragment-ordered store ----
    const int r0 = bid * 16;
    #pragma unroll
    for (int i = 0; i < 8; ++i) {
      int idx = i * 256 + tid;
      fr[idx & 127][idx >> 7] = fg[((size_t)r0 + (idx >> 7)) * ED + (idx & 127)];
    }
    __syncthreads();
    const int d = tid & 127, half = tid >> 7;
    float acc[8] = {};
    const float* w = W0 + XD * DD + d;
    for (int e = 0; e < ED; ++e) {
      float wv = w[e * DD];
      f32x4 f0 = *(const f32x4*)&fr[e][half * 8];
      f32x4 f1 = *(const f32x4*)&fr[e][half * 8 + 4];
      #pragma unroll
      for (int j = 0; j < 4; ++j) {
        acc[j]     = fmaf(f0[j], wv, acc[j]);
        acc[j + 4] = fmaf(f1[j], wv, acc[j + 4]);
      }
    }
    const int kk = d >> 5, lhi = (d >> 3) & 3, e2 = d & 7;
    #pragma unroll
    for (int j = 0; j < 8; ++j) {
      int R = r0 + half * 8 + j;          // global row = b*CL + c
      int b = R >> 9, c = R & 511;
      int t = c >> 7, cc = c & 127;
      int chunk = ((b * 4 + t) * 4 + kk) * 8 + (cc >> 6) * 4 + ((cc >> 4) & 3);
      fph[((size_t)chunk << 9) + ((size_t)(lhi * 16 + (cc & 15)) << 3) + e2] = (_Float16)acc[j];
    }
  } else if (bid < 160) {
    // ---- qp: 16 rows per block, linear store (b0 folded) ----
    const int r0 = (bid - 128) * 16;
    #pragma unroll
    for (int i = 0; i < 4; ++i) {
      int idx = i * 256 + tid;
      fr[idx & 63][idx >> 6] = qg[((size_t)r0 + (idx >> 6)) * XD + (idx & 63)];
    }
    __syncthreads();
    const int d = tid & 127, half = tid >> 7;
    float acc[8];
    float bv = b0[d];
    #pragma unroll
    for (int j = 0; j < 8; ++j) acc[j] = bv;
    const float* w = W0 + d;
    for (int e = 0; e < XD; ++e) {
      float wv = w[e * DD];
      f32x4 f0 = *(const f32x4*)&fr[e][half * 8];
      f32x4 f1 = *(const f32x4*)&fr[e][half * 8 + 4];
      #pragma unroll
      for (int j = 0; j < 4; ++j) {
        acc[j]     = fmaf(f0[j], wv, acc[j]);
        acc[j + 4] = fmaf(f1[j], wv, acc[j + 4]);
      }
    }
    #pragma unroll
    for (int j = 0; j < 8; ++j)
      qph[((size_t)r0 + half * 8 + j) * DD + d] = (_Float16)acc[j];
  } else {
    // ---- w1f: 8 blocks, LDS-staged coalesced fragment build ----
    const int id8 = bid - 160;            // 0..7
    const int wcol = id8 & 1, kk = id8 >> 1;
    #pragma unroll
    for (int i = 0; i < 8; ++i) {
      int idx = i * 256 + tid;            // 32 k-rows x 64 cols
      w1s[idx >> 6][idx & 63] = W1[(kk * 32 + (idx >> 6)) * DD + wcol * 64 + (idx & 63)];
    }
    __syncthreads();
    const int jt = tid >> 6, ln = tid & 63;
    const int llo = ln & 15, lhi = ln >> 4;
    f16x8 v;
    #pragma unroll
    for (int e = 0; e < 8; ++e)
      v[e] = (_Float16)w1s[lhi * 8 + e][jt * 16 + llo];
    *(f16x8*)(w1f + ((((size_t)wcol * 4 + kk) * 4 + jt) * 64 + ln) * 8) = v;
  }
}

// 512 blocks x 1024 threads (16 waves). Wave = (t, wrow, wcol): 64 MFMA each.
// 4 waves/SIMD (VGPR<=128) for latency hiding -- 2x the occupancy of R5.
__launch_bounds__(1024, 4)
__global__ void main_kernel(const float* __restrict__ logits,
                            const _Float16* __restrict__ fph,
                            const _Float16* __restrict__ qph,
                            const _Float16* __restrict__ w1f,
                            const float* __restrict__ b1,
                            const float* __restrict__ Wo,
                            const float* __restrict__ bo,
                            float* __restrict__ out) {
  __shared__ __align__(16) _Float16 wls[16384];   // 32 KB  W1 B-frags (linear copy)
  __shared__ __align__(16) float att[CL];         //  2 KB
  __shared__ float g[16][DD];                     //  8 KB
  __shared__ float gsum[DD];
  __shared__ float red[16];
  __shared__ float part[8][YD];                   //  1 KB

  const int tid = threadIdx.x;
  const int bid = blockIdx.x;            // b*QL + qi
  const int wid = tid >> 6, ln = tid & 63;
  const int b = bid >> 7;
  const int t = wid >> 2, wrow = (wid >> 1) & 1, wcol = wid & 1;
  const int lhi = ln >> 4, llo = ln & 15;

  // ---- stage W1 fragments: linear 32 KB copy (coalesced dwordx4) ----
  {
    const uint4* src = (const uint4*)w1f;
    uint4* dst = (uint4*)wls;
    dst[tid] = src[tid];
    dst[tid + 1024] = src[tid + 1024];
  }
  // ---- zero g ----
  ((float*)g)[tid] = 0.f;
  ((float*)g)[tid + 1024] = 0.f;

  // ---- softmax over 512 logits (waves 0..7) ----
  float sm_l = 0.f;
  if (tid < 512) {
    sm_l = logits[(size_t)bid * CL + tid];
    float m = sm_l;
    #pragma unroll
    for (int off = 1; off < 64; off <<= 1) m = fmaxf(m, __shfl_xor(m, off, 64));
    if (ln == 0) red[wid] = m;
  }
  __syncthreads();
  if (tid < 512) {
    float m = red[0];
    #pragma unroll
    for (int w = 1; w < 8; ++w) m = fmaxf(m, red[w]);
    float p = expf(sm_l - m);
    float s = p;
    #pragma unroll
    for (int off = 1; off < 64; off <<= 1) s += __shfl_xor(s, off, 64);
    if (ln == 0) red[8 + wid] = s;
    sm_l = p;                           // stash numerator
  }
  __syncthreads();
  if (tid < 512) {
    float tot = red[8];
    #pragma unroll
    for (int w = 9; w < 16; ++w) tot += red[w];
    att[tid] = sm_l / tot;
  }
  __syncthreads();                      // wls, att visible

  // ---- per-wave GEMM quadrant: 4kk x (4ct x 4jt) ----
  float b1v[4];
  #pragma unroll
  for (int jt = 0; jt < 4; ++jt) b1v[jt] = b1[wcol * 64 + jt * 16 + llo];

  f32x4 acc[4][4];
  #pragma unroll
  for (int ct = 0; ct < 4; ++ct)
    #pragma unroll
    for (int jt = 0; jt < 4; ++jt)
      acc[ct][jt] = (f32x4){b1v[jt], b1v[jt], b1v[jt], b1v[jt]};   // b1 folded

  const uint4* fpv = (const uint4*)fph;
  const _Float16* qrow = qph + (size_t)bid * DD;
  const f16x8 zf = {};

  #pragma unroll
  for (int kk = 0; kk < 4; ++kk) {
    const f16x8 qk = *(const f16x8*)(qrow + kk * 32 + lhi * 8);  // broadcast, L2-hot
    f16x8 a[4];
    #pragma unroll
    for (int ct = 0; ct < 4; ++ct) {
      const int chunk = ((b * 4 + t) * 4 + kk) * 8 + wrow * 4 + ct;
      uint4 u = fpv[chunk * 64 + ln];                  // coalesced 1KB/wave
      f16x8 x = *(const f16x8*)&u + qk;                // v_pk_add_f16
      a[ct] = __builtin_elementwise_max(x, zf);        // relu
    }
    #pragma unroll
    for (int jt = 0; jt < 4; ++jt) {
      f16x8 wv = *(const f16x8*)(wls + (size_t)((((wcol * 4 + kk) * 4 + jt) * 64 + ln) * 8));
      #pragma unroll
      for (int ct = 0; ct < 4; ++ct)
        acc[ct][jt] = __builtin_amdgcn_mfma_f32_16x16x32_f16(a[ct], wv, acc[ct][jt], 0, 0, 0);
    }
  }

  // ---- epilogue: gp[jt] = sum_c att[c]*relu(H2)  (Wo GEMM commuted away) ----
  float gp[4] = {0.f, 0.f, 0.f, 0.f};
  const int cb = t * 128 + wrow * 64 + lhi * 4;
  #pragma unroll
  for (int ct = 0; ct < 4; ++ct) {
    f32x4 a4 = *(const f32x4*)&att[cb + ct * 16];
    #pragma unroll
    for (int r = 0; r < 4; ++r)
      #pragma unroll
      for (int jt = 0; jt < 4; ++jt)
        gp[jt] = fmaf(a4[r], fmaxf(acc[ct][jt][r], 0.f), gp[jt]);
  }
  #pragma unroll
  for (int jt = 0; jt < 4; ++jt) {
    gp[jt] += __shfl_xor(gp[jt], 16, 64);
    gp[jt] += __shfl_xor(gp[jt], 32, 64);
  }
  if (ln < 16) {
    #pragma unroll
    for (int jt = 0; jt < 4; ++jt) g[wid][wcol * 64 + jt * 16 + ln] = gp[jt];
  }
  __syncthreads();

  // ---- reduce 16 waves, then y = gsum @ Wo + bo ----
  if (tid < 128) {
    float s = 0.f;
    #pragma unroll
    for (int w = 0; w < 16; ++w) s += g[w][tid];
    gsum[tid] = s;
  }
  __syncthreads();
  if (tid < 256) {
    const int ch = tid >> 5, y = tid & 31;
    float a = 0.f;
    #pragma unroll
    for (int jj = 0; jj < 16; ++jj) {
      int j = ch * 16 + jj;
      a = fmaf(gsum[j], Wo[j * YD + y], a);
    }
    part[ch][y] = a;
  }
  __syncthreads();
  if (tid < YD) {
    float a = bo[tid];
    #pragma unroll
    for (int ch = 0; ch < 8; ++ch) a += part[ch][tid];
    out[(size_t)bid * YD + tid] = a;
  }
}

extern "C" void kernel_launch(void* const* d_in, const int* in_sizes, int n_in,
                              void* d_out, int out_size, void* d_ws, size_t ws_size,
                              hipStream_t stream) {
  const float* q  = (const float*)d_in[0];
  const float* f  = (const float*)d_in[1];
  const float* lg = (const float*)d_in[2];
  const float* W0 = (const float*)d_in[3];
  const float* b0 = (const float*)d_in[4];
  const float* W1 = (const float*)d_in[5];
  const float* b1 = (const float*)d_in[6];
  const float* Wo = (const float*)d_in[7];
  const float* bo = (const float*)d_in[8];
  float* out = (float*)d_out;

  _Float16* fph = (_Float16*)d_ws;                         // 512 KB
  _Float16* qph = fph + (size_t)512 * 512;                 // 128 KB
  _Float16* w1f = qph + (size_t)B_ * QL * DD;              //  32 KB

  prep_kernel<<<168, 256, 0, stream>>>(q, f, W0, b0, W1, fph, qph, w1f);
  main_kernel<<<B_ * QL, 1024, 0, stream>>>(lg, fph, qph, w1f, b1, Wo, bo, out);
}

// Round 13
// 24.015 us; speedup vs baseline: 6.6415x; 1.1867x over previous
//
#include <hip/hip_runtime.h>

#define B_  4
#define QL  128
#define CL  512
#define XD  64
#define ED  128
#define DD  128
#define YD  32

typedef __attribute__((ext_vector_type(8))) _Float16 f16x8;
typedef __attribute__((ext_vector_type(4))) float f32x4;

// ws layout (16B-aligned):
//   fph : f16 [512 chunks][64 lanes][8 e] = 512 KB  fragment-ordered f-part
//         chunk = ((b*4+t)*4+kk)*8 + wrow*4 + ct ; holds
//         fp[b][t*128+wrow*64+ct*16+llo][kk*32+lhi*8+e] at lane lhi*16+llo, elem e
//   qph : f16 [B_*QL*DD] = 128 KB  q-part + b0, linear [row][d]
//   w1f : f16 [16384]    =  32 KB  W1 B-fragments [wcol][kk][jt][lane][e]
__global__ void prep_kernel(const float* __restrict__ qg,
                            const float* __restrict__ fg,
                            const float* __restrict__ W0,
                            const float* __restrict__ b0,
                            const float* __restrict__ W1,
                            _Float16* __restrict__ fph,
                            _Float16* __restrict__ qph,
                            _Float16* __restrict__ w1f) {
  const int bid = blockIdx.x, tid = threadIdx.x;
  __shared__ __align__(16) float fr[128][20];
  __shared__ float w1s[32][65];

  if (bid < 128) {
    // ---- fp: 16 global rows per block, fragment-ordered store ----
    const int r0 = bid * 16;
    #pragma unroll
    for (int i = 0; i < 8; ++i) {
      int idx = i * 256 + tid;
      fr[idx & 127][idx >> 7] = fg[((size_t)r0 + (idx >> 7)) * ED + (idx & 127)];
    }
    __syncthreads();
    const int d = tid & 127, half = tid >> 7;
    float acc[8] = {};
    const float* w = W0 + XD * DD + d;
    for (int e = 0; e < ED; ++e) {
      float wv = w[e * DD];
      f32x4 f0 = *(const f32x4*)&fr[e][half * 8];
      f32x4 f1 = *(const f32x4*)&fr[e][half * 8 + 4];
      #pragma unroll
      for (int j = 0; j < 4; ++j) {
        acc[j]     = fmaf(f0[j], wv, acc[j]);
        acc[j + 4] = fmaf(f1[j], wv, acc[j + 4]);
      }
    }
    const int kk = d >> 5, lhi = (d >> 3) & 3, e2 = d & 7;
    #pragma unroll
    for (int j = 0; j < 8; ++j) {
      int R = r0 + half * 8 + j;          // global row = b*CL + c
      int b = R >> 9, c = R & 511;
      int t = c >> 7, cc = c & 127;
      int chunk = ((b * 4 + t) * 4 + kk) * 8 + (cc >> 6) * 4 + ((cc >> 4) & 3);
      fph[((size_t)chunk << 9) + ((size_t)(lhi * 16 + (cc & 15)) << 3) + e2] = (_Float16)acc[j];
    }
  } else if (bid < 160) {
    // ---- qp: 16 rows per block, linear store (b0 folded) ----
    const int r0 = (bid - 128) * 16;
    #pragma unroll
    for (int i = 0; i < 4; ++i) {
      int idx = i * 256 + tid;
      fr[idx & 63][idx >> 6] = qg[((size_t)r0 + (idx >> 6)) * XD + (idx & 63)];
    }
    __syncthreads();
    const int d = tid & 127, half = tid >> 7;
    float acc[8];
    float bv = b0[d];
    #pragma unroll
    for (int j = 0; j < 8; ++j) acc[j] = bv;
    const float* w = W0 + d;
    for (int e = 0; e < XD; ++e) {
      float wv = w[e * DD];
      f32x4 f0 = *(const f32x4*)&fr[e][half * 8];
      f32x4 f1 = *(const f32x4*)&fr[e][half * 8 + 4];
      #pragma unroll
      for (int j = 0; j < 4; ++j) {
        acc[j]     = fmaf(f0[j], wv, acc[j]);
        acc[j + 4] = fmaf(f1[j], wv, acc[j + 4]);
      }
    }
    #pragma unroll
    for (int j = 0; j < 8; ++j)
      qph[((size_t)r0 + half * 8 + j) * DD + d] = (_Float16)acc[j];
  } else {
    // ---- w1f: 8 blocks, LDS-staged coalesced fragment build ----
    const int id8 = bid - 160;            // 0..7
    const int wcol = id8 & 1, kk = id8 >> 1;
    #pragma unroll
    for (int i = 0; i < 8; ++i) {
      int idx = i * 256 + tid;            // 32 k-rows x 64 cols
      w1s[idx >> 6][idx & 63] = W1[(kk * 32 + (idx >> 6)) * DD + wcol * 64 + (idx & 63)];
    }
    __syncthreads();
    const int jt = tid >> 6, ln = tid & 63;
    const int llo = ln & 15, lhi = ln >> 4;
    f16x8 v;
    #pragma unroll
    for (int e = 0; e < 8; ++e)
      v[e] = (_Float16)w1s[lhi * 8 + e][jt * 16 + llo];
    *(f16x8*)(w1f + ((((size_t)wcol * 4 + kk) * 4 + jt) * 64 + ln) * 8) = v;
  }
}

__launch_bounds__(256, 2)
__global__ void main_kernel(const float* __restrict__ logits,
                            const _Float16* __restrict__ fph,
                            const _Float16* __restrict__ qph,
                            const _Float16* __restrict__ w1f,
                            const float* __restrict__ b1,
                            const float* __restrict__ Wo,
                            const float* __restrict__ bo,
                            float* __restrict__ out) {
  __shared__ __align__(16) float att[CL];
  __shared__ float g[4][DD];
  __shared__ float red[8];
  __shared__ float part[8][YD];

  const int tid = threadIdx.x;
  const int bid = blockIdx.x;          // b*QL + qi
  const int wid = tid >> 6, ln = tid & 63;
  const int b = bid >> 7;
  const int wrow = wid >> 1, wcol = wid & 1;
  const int lhi = ln >> 4, llo = ln & 15;

  ((float*)g)[tid] = 0.f;
  ((float*)g)[tid + 256] = 0.f;

  // ---- W1 fragments -> registers (16 coalesced dwordx4, L2-broadcast) ----
  f16x8 wf[4][4];
  {
    const uint4* ws = (const uint4*)w1f;
    #pragma unroll
    for (int kk = 0; kk < 4; ++kk)
      #pragma unroll
      for (int jt = 0; jt < 4; ++jt) {
        uint4 u = ws[(((wcol * 4 + kk) * 4 + jt) << 6) + ln];
        wf[kk][jt] = *(const f16x8*)&u;
      }
  }
  // ---- qp fragment slices (broadcast 16B loads) ----
  f16x8 qpv[4];
  {
    const uint4* qs = (const uint4*)(qph + (size_t)bid * DD);
    #pragma unroll
    for (int kk = 0; kk < 4; ++kk) {
      uint4 u = qs[(kk * 32 + lhi * 8) >> 3];
      qpv[kk] = *(const f16x8*)&u;
    }
  }

  // ---- softmax over 512 logits ----
  {
    const float* lgr = logits + (size_t)bid * CL;
    float l0 = lgr[tid], l1 = lgr[tid + 256];
    float m = fmaxf(l0, l1);
    #pragma unroll
    for (int off = 1; off < 64; off <<= 1) m = fmaxf(m, __shfl_xor(m, off, 64));
    if (ln == 0) red[wid] = m;
    __syncthreads();
    m = fmaxf(fmaxf(red[0], red[1]), fmaxf(red[2], red[3]));
    float p0 = expf(l0 - m), p1 = expf(l1 - m);
    float s = p0 + p1;
    #pragma unroll
    for (int off = 1; off < 64; off <<= 1) s += __shfl_xor(s, off, 64);
    if (ln == 0) red[4 + wid] = s;
    __syncthreads();
    float inv = 1.f / (red[4] + red[5] + red[6] + red[7]);
    att[tid] = p0 * inv;
    att[tid + 256] = p1 * inv;
  }
  __syncthreads();   // att visible; no more barriers until output

  const int j0 = wcol * 64 + llo;
  float b1v[4];
  #pragma unroll
  for (int jt = 0; jt < 4; ++jt) b1v[jt] = b1[j0 + jt * 16];

  float gp[4] = {0.f, 0.f, 0.f, 0.f};
  const f16x8 zf = {};
  const uint4* fpv = (const uint4*)fph;

  #pragma unroll
  for (int t = 0; t < 4; ++t) {
    f32x4 acc[4][4];
    #pragma unroll
    for (int ct = 0; ct < 4; ++ct)
      #pragma unroll
      for (int jt = 0; jt < 4; ++jt)
        acc[ct][jt] = (f32x4){b1v[jt], b1v[jt], b1v[jt], b1v[jt]};   // b1 folded

    #pragma unroll
    for (int kk = 0; kk < 4; ++kk) {
      const int cb = ((((b * 4 + t) * 4 + kk) * 8 + wrow * 4) << 6);
      f16x8 a[4];
      #pragma unroll
      for (int ct = 0; ct < 4; ++ct) {
        uint4 u = fpv[cb + (ct << 6) + ln];                  // coalesced 1KB/wave
        f16x8 x = *(const f16x8*)&u + qpv[kk];               // v_pk_add_f16
        a[ct] = __builtin_elementwise_max(x, zf);            // relu
      }
      #pragma unroll
      for (int ct = 0; ct < 4; ++ct)
        #pragma unroll
        for (int jt = 0; jt < 4; ++jt)
          acc[ct][jt] = __builtin_amdgcn_mfma_f32_16x16x32_f16(a[ct], wf[kk][jt], acc[ct][jt], 0, 0, 0);
    }

    // epilogue: g[j] += att[c] * relu(H2)  (Wo GEMM commuted away; b1 in acc)
    const int cbase = t * 128 + wrow * 64 + lhi * 4;
    #pragma unroll
    for (int ct = 0; ct < 4; ++ct) {
      f32x4 a4 = *(const f32x4*)&att[cbase + ct * 16];
      #pragma unroll
      for (int r = 0; r < 4; ++r)
        #pragma unroll
        for (int jt = 0; jt < 4; ++jt)
          gp[jt] = fmaf(a4[r], fmaxf(acc[ct][jt][r], 0.f), gp[jt]);
    }
  }

  // reduce over lhi groups (same column j), then cross-wave via LDS
  #pragma unroll
  for (int jt = 0; jt < 4; ++jt) {
    gp[jt] += __shfl_xor(gp[jt], 16, 64);
    gp[jt] += __shfl_xor(gp[jt], 32, 64);
  }
  __syncthreads();
  if (ln < 16) {
    #pragma unroll
    for (int jt = 0; jt < 4; ++jt) g[wid][j0 + jt * 16] = gp[jt];
  }
  __syncthreads();

  // ---- y = g @ Wo + bo ----
  {
    int y = tid & 31, ch = tid >> 5;
    float a = 0.f;
    #pragma unroll
    for (int jj = 0; jj < 16; ++jj) {
      int j = ch * 16 + jj;
      float gj = g[0][j] + g[1][j] + g[2][j] + g[3][j];
      a = fmaf(gj, Wo[j * YD + y], a);
    }
    part[ch][y] = a;
  }
  __syncthreads();
  if (tid < YD) {
    float a = bo[tid];
    #pragma unroll
    for (int ch = 0; ch < 8; ++ch) a += part[ch][tid];
    out[(size_t)bid * YD + tid] = a;
  }
}

extern "C" void kernel_launch(void* const* d_in, const int* in_sizes, int n_in,
                              void* d_out, int out_size, void* d_ws, size_t ws_size,
                              hipStream_t stream) {
  const float* q  = (const float*)d_in[0];
  const float* f  = (const float*)d_in[1];
  const float* lg = (const float*)d_in[2];
  const float* W0 = (const float*)d_in[3];
  const float* b0 = (const float*)d_in[4];
  const float* W1 = (const float*)d_in[5];
  const float* b1 = (const float*)d_in[6];
  const float* Wo = (const float*)d_in[7];
  const float* bo = (const float*)d_in[8];
  float* out = (float*)d_out;

  _Float16* fph = (_Float16*)d_ws;                         // 512 KB
  _Float16* qph = fph + (size_t)512 * 512;                 // 128 KB
  _Float16* w1f = qph + (size_t)B_ * QL * DD;              //  32 KB

  prep_kernel<<<168, 256, 0, stream>>>(q, f, W0, b0, W1, fph, qph, w1f);
  main_kernel<<<B_ * QL, 256, 0, stream>>>(lg, fph, qph, w1f, b1, Wo, bo, out);
}